// Round 10
// baseline (124.189 us; speedup 1.0000x reference)
//
#include <hip/hip_runtime.h>

#define BB 32
#define MM 512
#define NN 4096
#define KK 4
#define MLO 0.999998f         // ~34 ulp margin: trigger has no false negatives
#define FG_BITS 0x3F19999A    // bit pattern of 0.6f

// All IoU values are >= +0.0f, so float ordering == signed-int ordering on the
// bit patterns, with -1 (int) as a below-everything sentinel.

__device__ __forceinline__ bool beatsI(int v1, int i1, int v2, int i2) {
    // total order: value descending, index ascending (JAX top_k tie-break)
    return (v1 > v2) || (v1 == v2 && i1 < i2);
}

__device__ __forceinline__ float rlane_f(float x, int idx) {
    return __int_as_float(__builtin_amdgcn_readlane(__float_as_int(x), idx));
}

// branchless compare-exchange keeping the winner in (av,ai)
#define CE(av, ai, bv, bi)                                        \
    {                                                             \
        bool _s = beatsI(bv, bi, av, ai);                         \
        int _mv = _s ? bv : av, _nv = _s ? av : bv;               \
        int _mi = _s ? bi : ai, _ni = _s ? ai : bi;               \
        av = _mv; bv = _nv; ai = _mi; bi = _ni;                   \
    }

struct T4 { int v0, v1, v2, v3; int i0, i1, i2, i3; float thr, c1; };

// ---------------------------------------------------------------------------
// Kernel A: per-gt top-4 (exact JAX top_k tie-break) + max_per_gt; zero counts.
// One wave handles 4 gt rows, wave-shared (uniform) top-4 state per gt.
// PRIME (j=0): exact iou all 64 lanes + bitonic butterfly -> uniform top-4
// (all lanes converge to identical state).
// STREAM (j>0): common path 12 branchless ops/gt, NO div, NO union:
//   trigger  IN*(1+thr) > thr*SS  (SS = ga+pa)  <=>  iou > v3  (+margin).
// Rare merges (R8 structure, best measured): parallel exec-masked exact div
// for all triggered lanes at once, then readlane-ordered serial insert.
// Margin: need trigger whenever RN(IN/u_ref) > v3, u_ref = max(RN(SS-IN),1e-9).
// thr = RN(v3*MLO) with MLO = 1-2^-19 absorbs the <=4 roundings in the test
// (proof sketch: each side perturbs by <= 3 ulp; 34-ulp slack dominates).
// Clamp corner only widens the trigger. Validated in production (round 9).
// ---------------------------------------------------------------------------
__global__ __launch_bounds__(512) void kernA(const float* __restrict__ gt,
                                             const float* __restrict__ pr,
                                             float* __restrict__ maxpg,
                                             float* __restrict__ topv,
                                             int* __restrict__ topi,
                                             int* __restrict__ counts) {
    __shared__ float4 pbox[NN];            // 64 KB, xyxy
    const int b = blockIdx.x >> 4;         // 16 blocks per batch (512 gts / 32)
    const int mblk = blockIdx.x & 15;
    const int tid = threadIdx.x;

    const float4* p4 = (const float4*)(pr + (size_t)b * NN * 4);
    #pragma unroll
    for (int i = 0; i < NN / 512; ++i) {
        int n = i * 512 + tid;
        float4 q = p4[n];
        // 0.5*w exact -> fma contraction harmless (identical rounding)
        pbox[n] = make_float4(q.x - 0.5f * q.z, q.y - 0.5f * q.w,
                              q.x + 0.5f * q.z, q.y + 0.5f * q.w);
    }
    __syncthreads();

    const int wave = tid >> 6, lane = tid & 63;
    const int mbase = mblk * 32 + wave * 4;
    const float4* g4 = (const float4*)(gt + (size_t)b * MM * 4);

#define GTDEF(G) \
    float gx1_##G, gy1_##G, gx2_##G, gy2_##G, ga_##G; \
    { float4 gg = g4[mbase + G]; \
      float x1 = gg.x - 0.5f * gg.z, y1 = gg.y - 0.5f * gg.w; \
      float x2 = gg.x + 0.5f * gg.z, y2 = gg.y + 0.5f * gg.w; \
      gx1_##G = x1; gy1_##G = y1; gx2_##G = x2; gy2_##G = y2; \
      ga_##G = __fmul_rn(x2 - x1, y2 - y1); }

    GTDEF(0) GTDEF(1) GTDEF(2) GTDEF(3)

    T4 t0, t1, t2, t3;

    // ---- PRIME (j = 0): exact iou all lanes, butterfly -> uniform top-4 ----
#define PIOU(G, VB) \
    int VB; \
    { float ltx = fmaxf(gx1_##G, q.x), lty = fmaxf(gy1_##G, q.y); \
      float rbx = fminf(gx2_##G, q.z), rby = fminf(gy2_##G, q.w); \
      float wc = fmaxf(rbx - ltx, 0.0f), hc = fmaxf(rby - lty, 0.0f); \
      float inter = __fmul_rn(wc, hc); \
      float u = fmaxf((ga_##G + pa) - inter, 1e-9f); \
      VB = __float_as_int(inter / u); }

#define PRIME(T, VB) \
    { int x0 = VB, x1 = -1, x2 = -1, x3 = -1; \
      int y0 = lane, y1 = 0x7fffffff, y2 = 0x7fffffff, y3 = 0x7fffffff; \
      for (int off = 1; off < 64; off <<= 1) { \
        int b0 = __shfl_xor(x0, off), b1 = __shfl_xor(x1, off); \
        int b2 = __shfl_xor(x2, off), b3 = __shfl_xor(x3, off); \
        int j0 = __shfl_xor(y0, off), j1 = __shfl_xor(y1, off); \
        int j2 = __shfl_xor(y2, off), j3 = __shfl_xor(y3, off); \
        int z4 = b3, z5 = b2, z6 = b1, z7 = b0; \
        int w4 = j3, w5 = j2, w6 = j1, w7 = j0; \
        CE(x0, y0, z4, w4); CE(x1, y1, z5, w5); \
        CE(x2, y2, z6, w6); CE(x3, y3, z7, w7); \
        CE(x0, y0, x2, y2); CE(x1, y1, x3, y3); \
        CE(x0, y0, x1, y1); CE(x2, y2, x3, y3); \
      } \
      T.v0 = x0; T.v1 = x1; T.v2 = x2; T.v3 = x3; \
      T.i0 = y0; T.i1 = y1; T.i2 = y2; T.i3 = y3; \
      T.thr = (T.v3 <= 0) ? 0.0f : __int_as_float(T.v3) * MLO; \
      T.c1 = 1.0f + T.thr; }

    {
        float4 q = pbox[lane];
        float pa = __fmul_rn(q.z - q.x, q.w - q.y);
        PIOU(0, vb0) PIOU(1, vb1) PIOU(2, vb2) PIOU(3, vb3)
        PRIME(t0, vb0) PRIME(t1, vb1) PRIME(t2, vb2) PRIME(t3, vb3)
    }

    // ---- STREAM (j = 1..63) ----
#define COMP(T, G, IN, SS, TR) \
    float IN, SS; bool TR; \
    { float ltx = fmaxf(gx1_##G, q.x), lty = fmaxf(gy1_##G, q.y); \
      float rbx = fminf(gx2_##G, q.z), rby = fminf(gy2_##G, q.w); \
      float wc = fmaxf(rbx - ltx, 0.0f), hc = fmaxf(rby - lty, 0.0f); \
      IN = __fmul_rn(wc, hc); \
      SS = ga_##G + pa; \
      TR = IN * T.c1 > T.thr * SS; }

    // Rare path: parallel exec-masked exact div, readlane-ordered insert.
#define MERGE(T, MK, IN, SS, TR) \
    if (MK) { \
      float iouv = 0.0f; \
      if (TR) { float uu = fmaxf(SS - IN, 1e-9f); iouv = IN / uu; } \
      unsigned long long mk = MK; \
      do { \
        int l = __ffsll((unsigned long long)mk) - 1; mk &= mk - 1; \
        int vb = (int)__builtin_amdgcn_readlane(__float_as_int(iouv), l); \
        if (vb > T.v3) {                          /* strict: exact tie rule */ \
          int n = nb + l; \
          bool c2 = vb > T.v2, c1c = vb > T.v1, c0 = vb > T.v0; \
          T.v3 = c2 ? T.v2 : vb;                T.i3 = c2 ? T.i2 : n; \
          T.v2 = c2 ? (c1c ? T.v1 : vb) : T.v2; T.i2 = c2 ? (c1c ? T.i1 : n) : T.i2; \
          T.v1 = c1c ? (c0 ? T.v0 : vb) : T.v1; T.i1 = c1c ? (c0 ? T.i0 : n) : T.i1; \
          T.v0 = c0 ? vb : T.v0;                T.i0 = c0 ? n : T.i0; \
        } \
      } while (mk); \
      T.thr = (T.v3 == 0) ? 0.0f : __int_as_float(T.v3) * MLO; \
      T.c1 = 1.0f + T.thr; \
    }

    for (int j = 1; j < NN / 64; ++j) {
        float4 q = pbox[j * 64 + lane];
        float pa = __fmul_rn(q.z - q.x, q.w - q.y);
        const int nb = j * 64;
        COMP(t0, 0, in0, ss0, tr0)
        COMP(t1, 1, in1, ss1, tr1)
        COMP(t2, 2, in2, ss2, tr2)
        COMP(t3, 3, in3, ss3, tr3)
        unsigned long long mk0 = __ballot(tr0), mk1 = __ballot(tr1);
        unsigned long long mk2 = __ballot(tr2), mk3 = __ballot(tr3);
        if ((mk0 | mk1) | (mk2 | mk3)) {       // single rare branch per iter
            MERGE(t0, mk0, in0, ss0, tr0)
            MERGE(t1, mk1, in1, ss1, tr1)
            MERGE(t2, mk2, in2, ss2, tr2)
            MERGE(t3, mk3, in3, ss3, tr3)
        }
    }

    if (lane == 0) {
#define WOUT(T, G) \
        { int gm = b * MM + mbase + G; \
          maxpg[gm] = __int_as_float(T.v0); \
          topv[gm * KK + 0] = __int_as_float(T.v0); \
          topv[gm * KK + 1] = __int_as_float(T.v1); \
          topv[gm * KK + 2] = __int_as_float(T.v2); \
          topv[gm * KK + 3] = __int_as_float(T.v3); \
          topi[gm * KK + 0] = T.i0; topi[gm * KK + 1] = T.i1; \
          topi[gm * KK + 2] = T.i2; topi[gm * KK + 3] = T.i3; \
          counts[gm] = 0; }
        WOUT(t0, 0) WOUT(t1, 1) WOUT(t2, 2) WOUT(t3, 3)
    }
}

// ---------------------------------------------------------------------------
// Kernel B: per-proposal argmax over gts (first-max), fg/lq, count scatter.
// 64 proposals per 256-thread block; wave q reduces gt quarter
// [128q,128q+128). LDS cost per m-step cut to ONE broadcast ds_read_b128:
// area & gmx live in per-lane REGISTER TABLES pulled by v_readlane with the
// uniform loop index (VALU pipe, not LDS -- round-9 analysis showed the
// b128+b64 pair put kernB at ~75% of the LDS issue ceiling).
// Quarters merged in m-order with strict > (first-max semantics). Grid 2048.
// ---------------------------------------------------------------------------
__global__ __launch_bounds__(256) void kernB(const float* __restrict__ gt,
                                             const float* __restrict__ pr,
                                             const float* __restrict__ maxpg,
                                             int* __restrict__ counts) {
    __shared__ float4 gbox[MM];            // xyxy, 8 KB
    __shared__ int sV[256], sI[256], sL[256];   // 3 KB
    const int b = blockIdx.x >> 6;         // 64 blocks per batch (4096/64)
    const int nblk = blockIdx.x & 63;
    const int tid = threadIdx.x;
    const float4* g4 = (const float4*)(gt + (size_t)b * MM * 4);

    for (int m = tid; m < MM; m += 256) {
        float4 gg = g4[m];
        gbox[m] = make_float4(gg.x - 0.5f * gg.z, gg.y - 0.5f * gg.w,
                              gg.x + 0.5f * gg.z, gg.y + 0.5f * gg.w);
    }

    const int lane = tid & 63;             // proposal within group
    const int qtr = tid >> 6;              // gt quarter == wave id
    const int m0 = qtr * 128;

    // Register tables: lane l holds area/gmx of gts m0+l and m0+64+l.
    // Area recomputed with reference rounding (identical to maxpg path).
    float arA, arB, gmA, gmB;
    {
        float4 g1 = g4[m0 + lane];
        float xa1 = g1.x - 0.5f * g1.z, ya1 = g1.y - 0.5f * g1.w;
        float xa2 = g1.x + 0.5f * g1.z, ya2 = g1.y + 0.5f * g1.w;
        arA = __fmul_rn(xa2 - xa1, ya2 - ya1);
        float4 g2 = g4[m0 + 64 + lane];
        float xb1 = g2.x - 0.5f * g2.z, yb1 = g2.y - 0.5f * g2.w;
        float xb2 = g2.x + 0.5f * g2.z, yb2 = g2.y + 0.5f * g2.w;
        arB = __fmul_rn(xb2 - xb1, yb2 - yb1);
        gmA = maxpg[b * MM + m0 + lane];
        gmB = maxpg[b * MM + m0 + 64 + lane];
    }
    __syncthreads();

    const int n = nblk * 64 + lane;
    float4 qq = ((const float4*)(pr + (size_t)b * NN * 4))[n];
    const float qx1 = qq.x - 0.5f * qq.z, qy1 = qq.y - 0.5f * qq.w;
    const float qx2 = qq.x + 0.5f * qq.z, qy2 = qq.y + 0.5f * qq.w;
    const float pa = __fmul_rn(qx2 - qx1, qy2 - qy1);

    // init (0, m0) is exact per quarter: iou >= 0; all-zero -> first of
    // quarter; cross-quarter strict > then yields the global first-max.
    float best = 0.0f;
    int bidx = m0;
    bool lq = false;

#define BODY(M, AR, GX) \
    { float4 gb = gbox[M]; \
      float ltx = fmaxf(gb.x, qx1), lty = fmaxf(gb.y, qy1); \
      float rbx = fminf(gb.z, qx2), rby = fminf(gb.w, qy2); \
      float w = fmaxf(rbx - ltx, 0.0f), h = fmaxf(rby - lty, 0.0f); \
      float inter = __fmul_rn(w, h); \
      float u = fmaxf((AR + pa) - inter, 1e-9f); \
      float iou = inter / u;            /* exact IEEE: rounded-tie semantics */ \
      bool c = iou > best;              /* first max kept, like jnp.argmax */ \
      best = c ? iou : best; \
      bidx = c ? (M) : bidx; \
      lq = lq || (iou == GX); }         /* exact equality vs per-gt max */

    #pragma unroll 4
    for (int mm = 0; mm < 64; ++mm) {
        float ar = rlane_f(arA, mm);
        float gx = rlane_f(gmA, mm);
        BODY(m0 + mm, ar, gx)
    }
    #pragma unroll 4
    for (int mm = 0; mm < 64; ++mm) {
        float ar = rlane_f(arB, mm);
        float gx = rlane_f(gmB, mm);
        BODY(m0 + 64 + mm, ar, gx)
    }

    sV[tid] = __float_as_int(best);
    sI[tid] = bidx;
    sL[tid] = lq ? 1 : 0;
    __syncthreads();

    if (tid < 64) {
        int v = sV[tid], i = sI[tid], L = sL[tid];
        #pragma unroll
        for (int q2 = 1; q2 < 4; ++q2) {
            int v2 = sV[tid + q2 * 64], i2 = sI[tid + q2 * 64];
            L |= sL[tid + q2 * 64];
            bool c = v2 > v;               // strict: lower quarter wins ties
            v = c ? v2 : v;
            i = c ? i2 : i;
        }
        if (v >= FG_BITS || L) {           // int cmp == float cmp (non-neg)
            atomicAdd(&counts[b * MM + i], 1);
        }
    }
}

// ---------------------------------------------------------------------------
// Kernel C: write the 4 concatenated float32 output sections.
// ---------------------------------------------------------------------------
__global__ __launch_bounds__(256) void kernC(const float* __restrict__ topv,
                                             const int* __restrict__ topi,
                                             const int* __restrict__ counts,
                                             float* __restrict__ out) {
    const int gm = blockIdx.x * 256 + threadIdx.x;   // 0 .. B*M-1
    if (gm >= BB * MM) return;
    const int cnt = counts[gm];
    const int m = gm & (MM - 1);
    float* sc = out;
    float* pi = out + (size_t)BB * MM * KK;
    float* gi = out + (size_t)2 * BB * MM * KK;
    float* va = out + (size_t)3 * BB * MM * KK;
    #pragma unroll
    for (int k = 0; k < KK; ++k) {
        const bool val = k < cnt;
        sc[gm * KK + k] = val ? topv[gm * KK + k] : 0.0f;
        pi[gm * KK + k] = (float)topi[gm * KK + k];
        gi[gm * KK + k] = (float)m;
        va[gm * KK + k] = val ? 1.0f : 0.0f;
    }
}

extern "C" void kernel_launch(void* const* d_in, const int* in_sizes, int n_in,
                              void* d_out, int out_size, void* d_ws, size_t ws_size,
                              hipStream_t stream) {
    const float* gt = (const float*)d_in[0];   // [B,M,4] cxcywh
    const float* pr = (const float*)d_in[1];   // [B,N,4] cxcywh
    // d_in[2] (gt_labels) is unused by the reference outputs.
    float* out = (float*)d_out;
    char* ws = (char*)d_ws;

    int*   counts = (int*)(ws);                 //  64 KB
    float* maxpg  = (float*)(ws + (1 << 16));   //  64 KB
    float* topv   = (float*)(ws + (2 << 16));   // 256 KB
    int*   topi   = (int*)(ws + (6 << 16));     // 256 KB

    kernA<<<BB * (MM / 32), 512, 0, stream>>>(gt, pr, maxpg, topv, topi, counts);
    kernB<<<BB * (NN / 64), 256, 0, stream>>>(gt, pr, maxpg, counts);
    kernC<<<(BB * MM + 255) / 256, 256, 0, stream>>>(topv, topi, counts, out);
}

// Round 11
// 118.254 us; speedup vs baseline: 1.0502x; 1.0502x over previous
//
#include <hip/hip_runtime.h>

#define BB 32
#define MM 512
#define NN 4096
#define KK 4
#define MLO 0.999998f         // ~34 ulp margin: trigger has no false negatives
#define FG_BITS 0x3F19999A    // bit pattern of 0.6f

// All IoU values are >= +0.0f, so float ordering == signed-int ordering on the
// bit patterns, with -1 (int) as a below-everything sentinel.

__device__ __forceinline__ int rfl(int x) {
    return __builtin_amdgcn_readfirstlane(x);
}

__device__ __forceinline__ bool beatsI(int v1, int i1, int v2, int i2) {
    // total order: value descending, index ascending (JAX top_k tie-break)
    return (v1 > v2) || (v1 == v2 && i1 < i2);
}

// branchless compare-exchange keeping the winner in (av,ai)
#define CE(av, ai, bv, bi)                                        \
    {                                                             \
        bool _s = beatsI(bv, bi, av, ai);                         \
        int _mv = _s ? bv : av, _nv = _s ? av : bv;               \
        int _mi = _s ? bi : ai, _ni = _s ? ai : bi;               \
        av = _mv; bv = _nv; ai = _mi; bi = _ni;                   \
    }

struct T4 { int v0, v1, v2, v3; int i0, i1, i2, i3; float thr, c1, thrga; };

// ---------------------------------------------------------------------------
// Kernel A: per-gt top-4 (exact JAX top_k tie-break) + max_per_gt; zero counts.
// One wave handles 2 gt rows; wave-shared top-4 state per gt. NO LDS: the
// proposals (64 KB/batch) are L2-resident; each wave streams them directly
// from global with a 1-deep pipeline (qn prefetch). 256-thread blocks,
// grid 2048 -> 32 waves/CU (round-10 had ~10 waves/CU and 70% VALUBusy with
// serial-merge gaps; more co-resident waves fill them).
// Common path per gt: 12 branchless ops, NO div, NO union:
//   trigger  IN*c1 > fma(thr, pa, thrga)   (c1 = 1+thr, thrga = thr*ga)
//   <=> approximately iou > v3, with MLO margin -> no false negatives;
//   false positives rejected exactly in MERGE. thr==0 -> IN>0, exact.
// Rare path (round-8/10 structure, best measured): parallel exec-masked
// exact IEEE div for all triggered lanes, readlane-ordered serial insert.
// ---------------------------------------------------------------------------
__global__ __launch_bounds__(256) void kernA(const float* __restrict__ gt,
                                             const float* __restrict__ pr,
                                             float* __restrict__ maxpg,
                                             float* __restrict__ topv,
                                             int* __restrict__ topi,
                                             int* __restrict__ counts) {
    const int b = blockIdx.x >> 6;         // 64 blocks per batch (512 gts / 8)
    const int mblk = blockIdx.x & 63;
    const int tid = threadIdx.x;
    const int wave = rfl(tid >> 6), lane = tid & 63;
    const int mbase = mblk * 8 + wave * 2; // 2 gts per wave
    const float4* g4 = (const float4*)(gt + (size_t)b * MM * 4);
    const float4* p4 = (const float4*)(pr + (size_t)b * NN * 4);

#define GTDEF(G) \
    float gx1_##G, gy1_##G, gx2_##G, gy2_##G, ga_##G; \
    { float4 gg = g4[mbase + G]; \
      float x1 = gg.x - 0.5f * gg.z, y1 = gg.y - 0.5f * gg.w; \
      float x2 = gg.x + 0.5f * gg.z, y2 = gg.y + 0.5f * gg.w; \
      gx1_##G = x1; gy1_##G = y1; gx2_##G = x2; gy2_##G = y2; \
      ga_##G = __fmul_rn(x2 - x1, y2 - y1); }

    GTDEF(0) GTDEF(1)

    T4 t0, t1;

    // ---- PRIME (j = 0): exact iou all lanes, butterfly -> uniform top-4 ----
#define PIOU(G, VB) \
    int VB; \
    { float ltx = fmaxf(gx1_##G, px1), lty = fmaxf(gy1_##G, py1); \
      float rbx = fminf(gx2_##G, px2), rby = fminf(gy2_##G, py2); \
      float wc = fmaxf(rbx - ltx, 0.0f), hc = fmaxf(rby - lty, 0.0f); \
      float inter = __fmul_rn(wc, hc); \
      float u = fmaxf((ga_##G + pa) - inter, 1e-9f); \
      VB = __float_as_int(inter / u); }

#define PRIME(T, VB, G) \
    { int x0 = VB, x1 = -1, x2 = -1, x3 = -1; \
      int y0 = lane, y1 = 0x7fffffff, y2 = 0x7fffffff, y3 = 0x7fffffff; \
      for (int off = 1; off < 64; off <<= 1) { \
        int b0 = __shfl_xor(x0, off), b1 = __shfl_xor(x1, off); \
        int b2 = __shfl_xor(x2, off), b3 = __shfl_xor(x3, off); \
        int j0 = __shfl_xor(y0, off), j1 = __shfl_xor(y1, off); \
        int j2 = __shfl_xor(y2, off), j3 = __shfl_xor(y3, off); \
        int z4 = b3, z5 = b2, z6 = b1, z7 = b0; \
        int w4 = j3, w5 = j2, w6 = j1, w7 = j0; \
        CE(x0, y0, z4, w4); CE(x1, y1, z5, w5); \
        CE(x2, y2, z6, w6); CE(x3, y3, z7, w7); \
        CE(x0, y0, x2, y2); CE(x1, y1, x3, y3); \
        CE(x0, y0, x1, y1); CE(x2, y2, x3, y3); \
      } \
      T.v0 = x0; T.v1 = x1; T.v2 = x2; T.v3 = x3; \
      T.i0 = y0; T.i1 = y1; T.i2 = y2; T.i3 = y3; \
      T.thr = (T.v3 <= 0) ? 0.0f : __int_as_float(T.v3) * MLO; \
      T.c1 = 1.0f + T.thr; T.thrga = T.thr * ga_##G; }

    {
        float4 qc = p4[lane];
        float px1 = qc.x - 0.5f * qc.z, py1 = qc.y - 0.5f * qc.w;
        float px2 = qc.x + 0.5f * qc.z, py2 = qc.y + 0.5f * qc.w;
        float pa = __fmul_rn(px2 - px1, py2 - py1);
        PIOU(0, vb0) PIOU(1, vb1)
        PRIME(t0, vb0, 0) PRIME(t1, vb1, 1)
    }

    // ---- STREAM (j = 1..63) ----
#define COMP(T, G, IN, TR) \
    float IN; bool TR; \
    { float ltx = fmaxf(gx1_##G, px1), lty = fmaxf(gy1_##G, py1); \
      float rbx = fminf(gx2_##G, px2), rby = fminf(gy2_##G, py2); \
      float wc = fmaxf(rbx - ltx, 0.0f), hc = fmaxf(rby - lty, 0.0f); \
      IN = __fmul_rn(wc, hc); \
      TR = IN * T.c1 > __fmaf_rn(T.thr, pa, T.thrga); }

    // Rare path: parallel exec-masked exact div, readlane-ordered insert.
#define MERGE(T, G, MK, IN, TR) \
    if (MK) { \
      float iouv = 0.0f; \
      if (TR) { float uu = fmaxf((ga_##G + pa) - IN, 1e-9f); iouv = IN / uu; } \
      unsigned long long mk = MK; \
      do { \
        int l = __ffsll((unsigned long long)mk) - 1; mk &= mk - 1; \
        int vb = (int)__builtin_amdgcn_readlane(__float_as_int(iouv), l); \
        if (vb > T.v3) {                          /* strict: exact tie rule */ \
          int n = nb + l; \
          bool c2 = vb > T.v2, c1c = vb > T.v1, c0 = vb > T.v0; \
          T.v3 = c2 ? T.v2 : vb;                T.i3 = c2 ? T.i2 : n; \
          T.v2 = c2 ? (c1c ? T.v1 : vb) : T.v2; T.i2 = c2 ? (c1c ? T.i1 : n) : T.i2; \
          T.v1 = c1c ? (c0 ? T.v0 : vb) : T.v1; T.i1 = c1c ? (c0 ? T.i0 : n) : T.i1; \
          T.v0 = c0 ? vb : T.v0;                T.i0 = c0 ? n : T.i0; \
        } \
      } while (mk); \
      T.thr = (T.v3 == 0) ? 0.0f : __int_as_float(T.v3) * MLO; \
      T.c1 = 1.0f + T.thr; T.thrga = T.thr * ga_##G; \
    }

    float4 qn = p4[64 + lane];
    for (int j = 1; j < 64; ++j) {
        float4 qc = qn;
        int jn = (j < 63) ? j + 1 : 63;
        qn = p4[jn * 64 + lane];           // prefetch next tile (L2-resident)
        float px1 = qc.x - 0.5f * qc.z, py1 = qc.y - 0.5f * qc.w;
        float px2 = qc.x + 0.5f * qc.z, py2 = qc.y + 0.5f * qc.w;
        float pa = __fmul_rn(px2 - px1, py2 - py1);
        const int nb = j * 64;
        COMP(t0, 0, in0, tr0)
        COMP(t1, 1, in1, tr1)
        unsigned long long mk0 = __ballot(tr0), mk1 = __ballot(tr1);
        if (mk0 | mk1) {                   // single rare branch per iter
            MERGE(t0, 0, mk0, in0, tr0)
            MERGE(t1, 1, mk1, in1, tr1)
        }
    }

    if (lane == 0) {
#define WOUT(T, G) \
        { int gm = b * MM + mbase + G; \
          maxpg[gm] = __int_as_float(T.v0); \
          topv[gm * KK + 0] = __int_as_float(T.v0); \
          topv[gm * KK + 1] = __int_as_float(T.v1); \
          topv[gm * KK + 2] = __int_as_float(T.v2); \
          topv[gm * KK + 3] = __int_as_float(T.v3); \
          topi[gm * KK + 0] = T.i0; topi[gm * KK + 1] = T.i1; \
          topi[gm * KK + 2] = T.i2; topi[gm * KK + 3] = T.i3; \
          counts[gm] = 0; }
        WOUT(t0, 0) WOUT(t1, 1)
    }
}

// ---------------------------------------------------------------------------
// Kernel B: per-proposal argmax over gts (first-max), fg/lq, count scatter.
// 64 proposals per 256-thread block; wave q reduces quarter [128q,128q+128).
// NO LDS in the loop: the quarter base is readfirstlane'd -> gt box + maxpg
// loads are provably wave-uniform -> scalar s_load on the SMEM pipe (free
// prefetch, no VGPR address calc, no LDS latency). Conversion to xyxy per
// m-step is ~7 wave-uniform VALU ops, identical rounding to kernA (0.5*w
// exact, explicit __fmul_rn). Quarters merged in m-order with strict >
// (first-max semantics). Grid 2048 -> 32 waves/CU.
// ---------------------------------------------------------------------------
__global__ __launch_bounds__(256) void kernB(const float* __restrict__ gt,
                                             const float* __restrict__ pr,
                                             const float* __restrict__ maxpg,
                                             int* __restrict__ counts) {
    __shared__ int sV[256], sI[256], sL[256];   // 3 KB
    const int b = blockIdx.x >> 6;         // 64 blocks per batch (4096/64)
    const int nblk = blockIdx.x & 63;
    const int tid = threadIdx.x;
    const int lane = tid & 63;
    const int qtru = rfl(tid >> 6);        // uniform quarter id
    const int m0 = qtru * 128;

    const float4* gq = (const float4*)(gt + ((size_t)b * MM + m0) * 4);
    const float*  mp = maxpg + b * MM + m0;

    const int n = nblk * 64 + lane;
    float4 qq = ((const float4*)(pr + (size_t)b * NN * 4))[n];
    const float qx1 = qq.x - 0.5f * qq.z, qy1 = qq.y - 0.5f * qq.w;
    const float qx2 = qq.x + 0.5f * qq.z, qy2 = qq.y + 0.5f * qq.w;
    const float pa = __fmul_rn(qx2 - qx1, qy2 - qy1);

    // init (0, m0) is exact per quarter: iou >= 0; all-zero -> first of
    // quarter; cross-quarter strict > then yields the global first-max.
    float best = 0.0f;
    int bidx = m0;
    bool lq = false;

    #pragma unroll 4
    for (int mm = 0; mm < 128; ++mm) {
        float4 gg = gq[mm];                // uniform -> s_load_dwordx4
        float gmx = mp[mm];                // uniform -> s_load_dword
        float x1 = gg.x - 0.5f * gg.z, y1 = gg.y - 0.5f * gg.w;
        float x2 = gg.x + 0.5f * gg.z, y2 = gg.y + 0.5f * gg.w;
        float ar = __fmul_rn(x2 - x1, y2 - y1);
        float ltx = fmaxf(x1, qx1), lty = fmaxf(y1, qy1);
        float rbx = fminf(x2, qx2), rby = fminf(y2, qy2);
        float w = fmaxf(rbx - ltx, 0.0f), h = fmaxf(rby - lty, 0.0f);
        float inter = __fmul_rn(w, h);
        float u = fmaxf((ar + pa) - inter, 1e-9f);
        float iou = inter / u;             // exact IEEE: rounded-tie semantics
        bool c = iou > best;               // first max kept, like jnp.argmax
        best = c ? iou : best;
        bidx = c ? (m0 + mm) : bidx;
        lq = lq || (iou == gmx);           // exact equality vs per-gt max
    }

    sV[tid] = __float_as_int(best);
    sI[tid] = bidx;
    sL[tid] = lq ? 1 : 0;
    __syncthreads();

    if (tid < 64) {
        int v = sV[tid], i = sI[tid], L = sL[tid];
        #pragma unroll
        for (int q2 = 1; q2 < 4; ++q2) {
            int v2 = sV[tid + q2 * 64], i2 = sI[tid + q2 * 64];
            L |= sL[tid + q2 * 64];
            bool c = v2 > v;               // strict: lower quarter wins ties
            v = c ? v2 : v;
            i = c ? i2 : i;
        }
        if (v >= FG_BITS || L) {           // int cmp == float cmp (non-neg)
            atomicAdd(&counts[b * MM + i], 1);
        }
    }
}

// ---------------------------------------------------------------------------
// Kernel C: write the 4 concatenated float32 output sections.
// ---------------------------------------------------------------------------
__global__ __launch_bounds__(256) void kernC(const float* __restrict__ topv,
                                             const int* __restrict__ topi,
                                             const int* __restrict__ counts,
                                             float* __restrict__ out) {
    const int gm = blockIdx.x * 256 + threadIdx.x;   // 0 .. B*M-1
    if (gm >= BB * MM) return;
    const int cnt = counts[gm];
    const int m = gm & (MM - 1);
    float* sc = out;
    float* pi = out + (size_t)BB * MM * KK;
    float* gi = out + (size_t)2 * BB * MM * KK;
    float* va = out + (size_t)3 * BB * MM * KK;
    #pragma unroll
    for (int k = 0; k < KK; ++k) {
        const bool val = k < cnt;
        sc[gm * KK + k] = val ? topv[gm * KK + k] : 0.0f;
        pi[gm * KK + k] = (float)topi[gm * KK + k];
        gi[gm * KK + k] = (float)m;
        va[gm * KK + k] = val ? 1.0f : 0.0f;
    }
}

extern "C" void kernel_launch(void* const* d_in, const int* in_sizes, int n_in,
                              void* d_out, int out_size, void* d_ws, size_t ws_size,
                              hipStream_t stream) {
    const float* gt = (const float*)d_in[0];   // [B,M,4] cxcywh
    const float* pr = (const float*)d_in[1];   // [B,N,4] cxcywh
    // d_in[2] (gt_labels) is unused by the reference outputs.
    float* out = (float*)d_out;
    char* ws = (char*)d_ws;

    int*   counts = (int*)(ws);                 //  64 KB
    float* maxpg  = (float*)(ws + (1 << 16));   //  64 KB
    float* topv   = (float*)(ws + (2 << 16));   // 256 KB
    int*   topi   = (int*)(ws + (6 << 16));     // 256 KB

    kernA<<<BB * (MM / 8), 256, 0, stream>>>(gt, pr, maxpg, topv, topi, counts);
    kernB<<<BB * (NN / 64), 256, 0, stream>>>(gt, pr, maxpg, counts);
    kernC<<<(BB * MM + 255) / 256, 256, 0, stream>>>(topv, topi, counts, out);
}